// Round 16
// baseline (673.222 us; speedup 1.0000x reference)
//
#include <hip/hip_runtime.h>
#include <hip/hip_fp16.h>

#define N_LINKS 262144
#define N_PAIRS 4194304
#define F 20
#define XB 20                   // X1 fp8 row stride in BYTES (packed, no pad)
#define T_ITERS 4

#define NSB 256                 // sectors (CSR build): sector = link >> 10
#define LPS 1024                // links per sector
#define PB 256                  // partition blocks
#define PT 1024                 // partition threads
#define PCHUNK (N_PAIRS / PB)   // 16384 pairs per partition block
#define PPT (PCHUNK / PT)       // 16 pairs per thread

typedef float f32x2 __attribute__((ext_vector_type(2)));
typedef _Float16 h16x2 __attribute__((ext_vector_type(2)));

__device__ __forceinline__ float selu_f(float x) {
    const float scale = 1.0507009873554805f;
    const float scale_alpha = 1.7580993408473766f;  // scale * alpha
    return x > 0.0f ? scale * x : scale_alpha * (__expf(x) - 1.0f);
}

// Branchless selu: sa*exp(min(x,0)) - sa + s*max(x,0). Exact at x=0 (exp(0)=1).
__device__ __forceinline__ float selu_b(float x) {
    const float s = 1.0507009873554805f;
    const float sa = 1.7580993408473766f;
    const float mx = fmaxf(x, 0.0f);
    const float mn = fminf(x, 0.0f);
    return fmaf(sa, __expf(mn), fmaf(s, mx, -sa));
}

__device__ __forceinline__ float sigmoid_f(float x) {
    return 1.0f / (1.0f + __expf(-x));
}

__device__ __forceinline__ float tanh_fast(float x) {
    x = fminf(fmaxf(x, -15.0f), 15.0f);
    float e = __expf(2.0f * x);
    return (e - 1.0f) / (e + 1.0f);
}

// Pack 20 floats -> 20 fp8 e4m3 bytes, one 20B row (5 dword stores, 4B aligned).
__device__ __forceinline__ void store_row_fp8(unsigned char* rowp, const float* o1) {
    int* p = (int*)rowp;
#pragma unroll
    for (int i = 0; i < 5; ++i) {
        int w = 0;
        w = __builtin_amdgcn_cvt_pk_fp8_f32(o1[4*i+0], o1[4*i+1], w, false);
        w = __builtin_amdgcn_cvt_pk_fp8_f32(o1[4*i+2], o1[4*i+3], w, true);
        p[i] = w;
    }
}

// ---------------- CSR build (once per call; graph is static) ----------------

__global__ void __launch_bounds__(PT)
k_part(const int* __restrict__ first, const int* __restrict__ second,
       int* __restrict__ ent, int* __restrict__ ptable, int* __restrict__ sectot) {
    __shared__ int hist[NSB];
    __shared__ int cur[NSB];
    const int b = blockIdx.x;
    const int cbase = b * PCHUNK;
    const int tid = threadIdx.x;
    for (int i = tid; i < NSB; i += PT) hist[i] = 0;
    __syncthreads();
    int sv[PPT];
#pragma unroll
    for (int k = 0; k < PPT; ++k) {
        sv[k] = second[cbase + k * PT + tid];
        atomicAdd(&hist[sv[k] >> 10], 1);
    }
    __syncthreads();
    if (tid < NSB) {
        int acc = 0;
        for (int j = 0; j < tid; ++j) acc += hist[j];   // excl scan, 256 bins
        cur[tid] = acc;
        ptable[b * (NSB + 1) + tid] = acc;
        if (tid == 0) ptable[b * (NSB + 1) + NSB] = PCHUNK;
        atomicAdd(&sectot[tid], hist[tid]);
    }
    __syncthreads();
#pragma unroll
    for (int k = 0; k < PPT; ++k) {
        const int s = sv[k];
        const int f = first[cbase + k * PT + tid];
        const int pos = atomicAdd(&cur[s >> 10], 1);
        ent[cbase + pos] = f | ((s & 1023) << 18);
    }
}

__global__ void k_scan256(const int* __restrict__ sectot, int* __restrict__ sbase,
                          int* __restrict__ rs) {
    __shared__ int s[NSB];
    const int t = threadIdx.x;
    s[t] = sectot[t];
    __syncthreads();
    if (t == 0) {
        int acc = 0;
        for (int j = 0; j < NSB; ++j) { int c = s[j]; s[j] = acc; acc += c; }
    }
    __syncthreads();
    sbase[t] = s[t];
    if (t == 0) { sbase[NSB] = N_PAIRS; rs[N_LINKS] = N_PAIRS; }
}

// Degree-sort per sector; emits rank-ordered rs, lid[rank]=link, rnk[link]=rank
// (direct inverse write, no separate k_inv). srcs hold RAW link ids; k_remap
// converts to rank*20 afterwards.
__global__ void __launch_bounds__(PT)
k_build(const int* __restrict__ ptable, const int* __restrict__ sbase,
        const int* __restrict__ ent, int* __restrict__ srcs, int* __restrict__ rs,
        int* __restrict__ lid, int* __restrict__ rnk_g) {
    __shared__ int rstart[PB];
    __shared__ int rlen[PB];
    __shared__ int lcnt[LPS];
    __shared__ int cur[LPS];
    __shared__ int dhist[64];
    __shared__ int dbase[64];
    __shared__ int dcur[64];
    const int sb = blockIdx.x;
    const int tid = threadIdx.x;
    if (tid < PB) {
        const int o0 = ptable[tid * (NSB + 1) + sb];
        const int o1 = ptable[tid * (NSB + 1) + sb + 1];
        rstart[tid] = tid * PCHUNK + o0;
        rlen[tid] = o1 - o0;
    }
    lcnt[tid] = 0;                       // PT == LPS
    if (tid < 64) { dhist[tid] = 0; dcur[tid] = 0; }
    __syncthreads();
    const int wave = tid >> 6;
    const int lane = tid & 63;
    for (int j = wave; j < PB; j += (PT >> 6)) {
        const int r0 = rstart[j], rl = rlen[j];
        for (int i = lane; i < rl; i += 64)
            atomicAdd(&lcnt[(ent[r0 + i] >> 18) & 1023], 1);
    }
    __syncthreads();
    const int count = lcnt[tid];
    const int dbin = min(count, 63);
    atomicAdd(&dhist[dbin], 1);
    __syncthreads();
    if (tid == 0) {
        int acc = 0;
        for (int b = 0; b < 64; ++b) { dbase[b] = acc; acc += dhist[b]; }
    }
    __syncthreads();
    const int rank = dbase[dbin] + atomicAdd(&dcur[dbin], 1);
    lcnt[rank] = count;                  // re-key counts into rank order
    lid[sb * LPS + rank] = sb * LPS + tid;
    rnk_g[sb * LPS + tid] = sb * LPS + rank;
    __syncthreads();
    for (int off = 1; off < LPS; off <<= 1) {   // inclusive Hillis-Steele scan
        const int v = (tid >= off) ? lcnt[tid - off] : 0;
        __syncthreads();
        lcnt[tid] += v;
        __syncthreads();
    }
    const int sbb = sbase[sb];
    const int excl = lcnt[rank] - count;
    rs[sb * LPS + rank] = sbb + excl;
    cur[tid] = excl;                     // cur stays in tid (link) space
    __syncthreads();
    for (int j = wave; j < PB; j += (PT >> 6)) {
        const int r0 = rstart[j], rl = rlen[j];
        for (int i = lane; i < rl; i += 64) {
            const int e = ent[r0 + i];
            const int pos = atomicAdd(&cur[(e >> 18) & 1023], 1);
            srcs[sbb + pos] = e & 0x3FFFF;   // raw link id
        }
    }
}

// srcs: raw link id -> rank*20 (prescaled byte base into rank-space X1b).
__global__ void k_remap(int* __restrict__ srcs, const int* __restrict__ rnk) {
    const int p = blockIdx.x * blockDim.x + threadIdx.x;
    srcs[p] = rnk[srcs[p]] * 20;
}

// ---------------- per-iteration kernels ----------------

// Slot-indexed premsg (t=0): link = lid[slot]; gathers link_state row, writes
// X1b/X2h at slot (rank space) AND copies the row into state_r[slot].
__global__ void k_premsg(const float* __restrict__ link_state,
                         const int* __restrict__ lid,
                         const float* __restrict__ W_msg,
                         const float* __restrict__ b_msg,
                         unsigned char* __restrict__ X1b, __half* __restrict__ X2h,
                         float* __restrict__ state_r) {
    __shared__ float Wl[F * 2 * F];
    __shared__ float bl[F];
    for (int i = threadIdx.x; i < F * 2 * F; i += blockDim.x) Wl[i] = W_msg[i];
    if (threadIdx.x < F) bl[threadIdx.x] = b_msg[threadIdx.x];
    __syncthreads();

    const int slot = blockIdx.x * blockDim.x + threadIdx.x;
    const int link = lid[slot];

    float s[F];
    const float4* sp = (const float4*)(link_state + (size_t)link * F);
    float4* so = (float4*)(state_r + (size_t)slot * F);
#pragma unroll
    for (int i = 0; i < 5; ++i) {
        float4 v = sp[i];
        so[i] = v;
        s[4*i+0] = v.x; s[4*i+1] = v.y; s[4*i+2] = v.z; s[4*i+3] = v.w;
    }
    float o1[F], o2[F];
#pragma unroll
    for (int o = 0; o < F; ++o) {
        float a1 = bl[o], a2 = 0.0f;
#pragma unroll
        for (int k = 0; k < F; ++k) {
            a1 = fmaf(Wl[o * 2 * F + k],     s[k], a1);
            a2 = fmaf(Wl[o * 2 * F + F + k], s[k], a2);
        }
        o1[o] = a1; o2[o] = a2;
    }
    store_row_fp8(X1b + (size_t)slot * XB, o1);
    __half2* xp = (__half2*)(X2h + (size_t)slot * F);
#pragma unroll
    for (int i = 0; i < 10; ++i)
        xp[i] = __halves2half2(__float2half(o2[2*i]), __float2half(o2[2*i+1]));
}

// FUSED per-iteration kernel: aggregate + GRU + next-iter premsg + feature.
// Wave owns 6 rank-consecutive slots; lane = g*10+j; group g owns slot lb+g;
// lane j owns features 2j,2j+1.
// Phase 1: gather-aggregate into registers (m stays on-chip; no agg array).
// Phase 2: broadcast m/h across the group (40 shuffles), GRU via LDS fp16
// dot2s, write state[slot]; premsg for next iter into X1nxt (double-buffered
// so other blocks' phase-1 gathers of X1cur never see partial writes) + X2h
// (own-slot only, read-then-write by the same wave). Feature reduce on last.
__global__ void __launch_bounds__(256)
k_step(const int* __restrict__ rs, const int* __restrict__ srcs,
       const unsigned char* __restrict__ X1cur, unsigned char* __restrict__ X1nxt,
       __half* __restrict__ X2h, float* __restrict__ state,
       const float* __restrict__ W_ih, const float* __restrict__ W_hh,
       const float* __restrict__ b_ih, const float* __restrict__ b_hh,
       const float* __restrict__ W_msg, const float* __restrict__ b_msg,
       float* __restrict__ feature, int flags) {
    __shared__ h16x2 WiH[3 * F * 10];   // row (gate*F+o): 10 half2 = 20 weights
    __shared__ h16x2 WhH[3 * F * 10];
    __shared__ h16x2 WmH[F * 20];       // row o: k 0..9 = W1, 10..19 = W2
    __shared__ float bi[3 * F];
    __shared__ float bh[3 * F];
    __shared__ float bm[F];
    __shared__ float red[F];
    {
        _Float16* wi = (_Float16*)WiH;
        _Float16* wh = (_Float16*)WhH;
        for (int i = threadIdx.x; i < 3 * F * F; i += 256) {
            wi[i] = (_Float16)W_ih[i];
            wh[i] = (_Float16)W_hh[i];
        }
        _Float16* wm = (_Float16*)WmH;
        for (int i = threadIdx.x; i < F * 2 * F; i += 256)
            wm[i] = (_Float16)W_msg[i];
    }
    if (threadIdx.x < 3 * F) {
        bi[threadIdx.x] = b_ih[threadIdx.x];
        bh[threadIdx.x] = b_hh[threadIdx.x];
    }
    if (threadIdx.x < F) {
        bm[threadIdx.x] = b_msg[threadIdx.x];
        red[threadIdx.x] = 0.0f;
    }
    __syncthreads();

    const int wave = threadIdx.x >> 6;
    const int lane = threadIdx.x & 63;
    const int g = lane / 10;          // 0..5 active, 6 = idle (lanes 60-63)
    const int j = lane - g * 10;      // 0..9
    const int gsel = (g < 6) ? g : 5;
    const int slot = (blockIdx.x * 4 + wave) * 6 + gsel;
    const bool active = (g < 6) && (slot < N_LINKS);
    const int sc = min(slot, N_LINKS - 1);

    const int row_start = rs[sc];
    const int cnt = active ? (rs[sc + 1] - row_start) : 0;
    const int cl = (cnt > 0) ? (cnt - 1) : 0;

    const __half2 hv = *(const __half2*)(X2h + (size_t)sc * F + 2 * j);
    const float x2a = __half2float(__low2half(hv));
    const float x2b = __half2float(__high2half(hv));

    // ---- phase 1: gather-aggregate (m in registers) ----
    int cmax = cnt;
#pragma unroll
    for (int off = 1; off < 64; off <<= 1)
        cmax = max(cmax, __shfl_xor(cmax, off, 64));

    float acc_a = 0.0f, acc_b = 0.0f;
    for (int base = 0; base < cmax; base += 10) {
        const int sv = srcs[row_start + min(base + j, cl)];  // batch preload
#pragma unroll
        for (int r = 0; r < 10; ++r) {
            const int src = __shfl(sv, gsel * 10 + r, 64);   // prescaled rank*20
            const unsigned v = *(const unsigned short*)(X1cur + src + 2 * j);
            const f32x2 xx = __builtin_amdgcn_cvt_pk_f32_fp8((int)v, false);
            const bool ok = (base + r) < cnt;
            acc_a += ok ? selu_b(xx[0] + x2a) : 0.0f;
            acc_b += ok ? selu_b(xx[1] + x2b) : 0.0f;
        }
    }

    // ---- phase 2: GRU ----
    const float2 hown = *(const float2*)(state + (size_t)sc * F + 2 * j);
    const int gb = gsel * 10;
    h16x2 mh[10], hh[10];
#pragma unroll
    for (int kk = 0; kk < 10; ++kk) {
        const float ma = __shfl(acc_a, gb + kk, 64);
        const float mb = __shfl(acc_b, gb + kk, 64);
        const float ha = __shfl(hown.x, gb + kk, 64);
        const float hb = __shfl(hown.y, gb + kk, 64);
        mh[kk][0] = (_Float16)ma; mh[kk][1] = (_Float16)mb;
        hh[kk][0] = (_Float16)ha; hh[kk][1] = (_Float16)hb;
    }

    float hnv[2];
    const float how[2] = {hown.x, hown.y};
#pragma unroll
    for (int t2 = 0; t2 < 2; ++t2) {
        const int o = 2 * j + t2;
        float gri = 0.f, gzi = 0.f, gin = bi[2*F + o];
        float grh = 0.f, gzh = 0.f, ghn = bh[2*F + o];
#pragma unroll
        for (int kk = 0; kk < 10; ++kk) {
            gri = __builtin_amdgcn_fdot2(WiH[(0*F + o) * 10 + kk], mh[kk], gri, false);
            gzi = __builtin_amdgcn_fdot2(WiH[(1*F + o) * 10 + kk], mh[kk], gzi, false);
            gin = __builtin_amdgcn_fdot2(WiH[(2*F + o) * 10 + kk], mh[kk], gin, false);
            grh = __builtin_amdgcn_fdot2(WhH[(0*F + o) * 10 + kk], hh[kk], grh, false);
            gzh = __builtin_amdgcn_fdot2(WhH[(1*F + o) * 10 + kk], hh[kk], gzh, false);
            ghn = __builtin_amdgcn_fdot2(WhH[(2*F + o) * 10 + kk], hh[kk], ghn, false);
        }
        const float r = sigmoid_f(bi[o] + bh[o] + gri + grh);
        const float z = sigmoid_f(bi[F + o] + bh[F + o] + gzi + gzh);
        const float n = tanh_fast(gin + r * ghn);
        hnv[t2] = (1.0f - z) * n + z * how[t2];
    }
    if (active) {
        float2 o; o.x = hnv[0]; o.y = hnv[1];
        *(float2*)(state + (size_t)slot * F + 2 * j) = o;
    }

    if (flags & 1) {  // premsg for next iteration
        h16x2 hnh[10];
#pragma unroll
        for (int kk = 0; kk < 10; ++kk) {
            const float na = __shfl(hnv[0], gb + kk, 64);
            const float nb = __shfl(hnv[1], gb + kk, 64);
            hnh[kk][0] = (_Float16)na; hnh[kk][1] = (_Float16)nb;
        }
        float o1v[2], o2v[2];
#pragma unroll
        for (int t2 = 0; t2 < 2; ++t2) {
            const int o = 2 * j + t2;
            float a1 = bm[o], a2 = 0.0f;
#pragma unroll
            for (int kk = 0; kk < 10; ++kk) {
                a1 = __builtin_amdgcn_fdot2(WmH[o * 20 + kk],      hnh[kk], a1, false);
                a2 = __builtin_amdgcn_fdot2(WmH[o * 20 + 10 + kk], hnh[kk], a2, false);
            }
            o1v[t2] = a1; o2v[t2] = a2;
        }
        if (active) {
            const int w = __builtin_amdgcn_cvt_pk_fp8_f32(o1v[0], o1v[1], 0, false);
            *(unsigned short*)(X1nxt + (size_t)slot * XB + 2 * j) = (unsigned short)w;
            *(__half2*)(X2h + (size_t)slot * F + 2 * j) =
                __halves2half2(__float2half(o2v[0]), __float2half(o2v[1]));
        }
    }

    if (flags & 2) {  // feature reduction: sum hn over all links
        if (active) {
            atomicAdd(&red[2 * j],     hnv[0]);
            atomicAdd(&red[2 * j + 1], hnv[1]);
        }
        __syncthreads();
        if (threadIdx.x < F) atomicAdd(&feature[threadIdx.x], red[threadIdx.x]);
    }
}

__global__ void k_readout(const float* __restrict__ feature,
                          const float* __restrict__ W_r1, const float* __restrict__ b_r1,
                          const float* __restrict__ W_r2, const float* __restrict__ b_r2,
                          const float* __restrict__ W_out, const float* __restrict__ b_out,
                          float* __restrict__ out) {
    if (threadIdx.x != 0 || blockIdx.x != 0) return;
    float fv[F], h1[F], h2[F];
#pragma unroll
    for (int i = 0; i < F; ++i) fv[i] = feature[i];
#pragma unroll
    for (int o = 0; o < F; ++o) {
        float a = b_r1[o];
#pragma unroll
        for (int k = 0; k < F; ++k) a = fmaf(W_r1[o * F + k], fv[k], a);
        h1[o] = selu_f(a);
    }
#pragma unroll
    for (int o = 0; o < F; ++o) {
        float a = b_r2[o];
#pragma unroll
        for (int k = 0; k < F; ++k) a = fmaf(W_r2[o * F + k], h1[k], a);
        h2[o] = selu_f(a);
    }
    float a = b_out[0];
#pragma unroll
    for (int k = 0; k < F; ++k) a = fmaf(W_out[k], h2[k], a);
    out[0] = a;
}

extern "C" void kernel_launch(void* const* d_in, const int* in_sizes, int n_in,
                              void* d_out, int out_size, void* d_ws, size_t ws_size,
                              hipStream_t stream) {
    const float* link_state = (const float*)d_in[0];
    const int*   first      = (const int*)  d_in[1];
    const int*   second     = (const int*)  d_in[2];
    // d_in[3] = state_dim (unused)
    const float* W_msg = (const float*)d_in[4];
    const float* b_msg = (const float*)d_in[5];
    const float* W_ih  = (const float*)d_in[6];
    const float* W_hh  = (const float*)d_in[7];
    const float* b_ih  = (const float*)d_in[8];
    const float* b_hh  = (const float*)d_in[9];
    const float* W_r1  = (const float*)d_in[10];
    const float* b_r1  = (const float*)d_in[11];
    const float* W_r2  = (const float*)d_in[12];
    const float* b_r2  = (const float*)d_in[13];
    const float* W_out = (const float*)d_in[14];
    const float* b_out = (const float*)d_in[15];
    float* out = (float*)d_out;

    const size_t NF = (size_t)N_LINKS * F;
    float* state = (float*)d_ws;                            // 21 MB (rank space)
    unsigned char* X1b0 = (unsigned char*)(state + NF);     // 5.25 MB
    unsigned char* X1b1 = X1b0 + (size_t)N_LINKS * XB;      // 5.25 MB
    __half* X2h = (__half*)(X1b1 + (size_t)N_LINKS * XB);   // 10.5 MB
    int* srcs   = (int*)(X2h + NF);                         // 16.8 MB
    int* rs     = srcs + N_PAIRS;                           // 1 MB (+1)
    int* lid    = rs + N_LINKS + 1;                         // 1 MB
    int* rnk    = lid + N_LINKS;                            // 1 MB
    float* feature = (float*)(rnk + N_LINKS);               // 128 B slot
    int* ptable = (int*)(feature + 32);                     // 256*(256+1) ints
    int* sectot = ptable + PB * (NSB + 1);                  // 256 ints
    int* sbase  = sectot + NSB;                             // 257 ints
    int* ent    = (int*)X1b0;   // aliases X1b0|X1b1|X2h (21 MB); dead after build

    hipMemsetAsync(sectot, 0, NSB * sizeof(int), stream);
    hipMemsetAsync(feature, 0, F * sizeof(float), stream);

    k_part<<<PB, PT, 0, stream>>>(first, second, ent, ptable, sectot);
    k_scan256<<<1, NSB, 0, stream>>>(sectot, sbase, rs);
    k_build<<<NSB, PT, 0, stream>>>(ptable, sbase, ent, srcs, rs, lid, rnk);
    k_remap<<<N_PAIRS / 256, 256, 0, stream>>>(srcs, rnk);

    k_premsg<<<N_LINKS / 256, 256, 0, stream>>>(link_state, lid, W_msg, b_msg,
                                                X1b0, X2h, state);

    unsigned char* bufs[2] = {X1b0, X1b1};
    const int stepBlocks = (N_LINKS + 23) / 24;  // 4 waves x 6 slots per block
    for (int t = 0; t < T_ITERS; ++t) {
        int flags = (t < T_ITERS - 1 ? 1 : 0) | (t == T_ITERS - 1 ? 2 : 0);
        k_step<<<stepBlocks, 256, 0, stream>>>(rs, srcs, bufs[t & 1], bufs[(t + 1) & 1],
                                               X2h, state, W_ih, W_hh, b_ih, b_hh,
                                               W_msg, b_msg, feature, flags);
    }
    k_readout<<<1, 64, 0, stream>>>(feature, W_r1, b_r1, W_r2, b_r2, W_out, b_out, out);
}